// Round 12
// baseline (489.536 us; speedup 1.0000x reference)
//
#include <hip/hip_runtime.h>
#include <hip/hip_bf16.h>

typedef __attribute__((ext_vector_type(4))) float f32x4;
typedef __attribute__((ext_vector_type(8))) short bf16x8;
typedef __attribute__((ext_vector_type(4))) unsigned short ush4;

#define GAS __attribute__((address_space(1)))
#define LAS __attribute__((address_space(3)))

__device__ __forceinline__ unsigned int cvtpk(float lo, float hi) {
  unsigned int r;
  asm("v_cvt_pk_bf16_f32 %0, %1, %2" : "=v"(r) : "v"(lo), "v"(hi));
  return r;
}
__device__ __forceinline__ unsigned short f2bf(float f) { return (unsigned short)cvtpk(f, f); }
__device__ __forceinline__ f32x4 mfma16(bf16x8 a, bf16x8 b, f32x4 c) {
  return __builtin_amdgcn_mfma_f32_16x16x32_bf16(a, b, c, 0, 0, 0);
}
__device__ __forceinline__ void gl_lds16(const unsigned short* g, unsigned short* l) {
  __builtin_amdgcn_global_load_lds((const GAS unsigned short*)g, (LAS unsigned short*)l, 16, 0, 0);
}
__device__ __forceinline__ void memfence_sched() { asm volatile("" ::: "memory"); }

__global__ __launch_bounds__(256)
void cvt_f32_bf16(const float* __restrict__ in, unsigned short* __restrict__ out, int n8) {
  for (int i = blockIdx.x * blockDim.x + threadIdx.x; i < n8; i += gridDim.x * blockDim.x) {
    const float4 a = *reinterpret_cast<const float4*>(in + (size_t)i * 8);
    const float4 b = *reinterpret_cast<const float4*>(in + (size_t)i * 8 + 4);
    uint4 o;
    o.x = cvtpk(a.x, a.y); o.y = cvtpk(a.z, a.w);
    o.z = cvtpk(b.x, b.y); o.w = cvtpk(b.z, b.w);
    *reinterpret_cast<uint4*>(out + (size_t)i * 8) = o;
  }
}

// C[M,N] = A[M,512] @ B[N,512]^T, 256x256 tile, BK=32, 16 K-tiles,
// 512 thr (8 waves 2x4), per-wave 128x64.
// AF32: A staged to LDS as RAW FP32 via global_load_lds ([256][32] f32,
// 32 KB/tile, XOR key r&7 on 16B chunks), converted at frag-read with
// v_cvt_pk_bf16_f32. B bf16 gl_lds ([256][32] bf16, key r&3).
// NBUF=3 (A 96 KB + B 48 KB = 144 KB, 1 blk/CU). Iter kt: STAGE(kt+2)
// (targets slot freed at barrier kt-1 -> skew-safe), frag reads + cvt,
// lgkmcnt(0)+sched_barrier, 32 MFMA in setprio, vmcnt(LPT) counted
// (kt+1 landed, kt+2 in flight -> never drains), barrier. (T3/T4/T5)
// MODE 0: bf16 out *0.125 ; MODE 2: f32 out + bias ;
// MODE 3: fused kv epilogue (k rows + vT transpose, LDS bounce).
template<int MODE, bool AF32>
__global__ __launch_bounds__(512, 1)
void gemmF(const void* __restrict__ Agv, const unsigned short* __restrict__ Bg,
           void* __restrict__ Cg, void* __restrict__ Cg2,
           const float* __restrict__ bias, int ntn, size_t ldc)
{
  constexpr int ASLOT = AF32 ? 16384 : 8192;   // ush per A K-tile slot
  constexpr int LPT = AF32 ? 6 : 4;            // gl_lds loads per K-tile (A+B)
  __shared__ unsigned short sm[3 * ASLOT + 3 * 8192];
  unsigned short* const smB = sm + 3 * ASLOT;

  const int t = threadIdx.x, lane = t & 63, w = t >> 6;
  const int lo = lane & 15, hi = lane >> 4;
  const int wm = w >> 2, wn = w & 3;
  const int nwg = gridDim.x, bid = blockIdx.x;
  const int id = (bid & 7) * (nwg >> 3) + (bid >> 3);   // XCD swizzle (nwg%8==0)
  const int row0 = (id / ntn) * 256, col0 = (id % ntn) * 256;

  const float* Af = (const float*)Agv;
  const unsigned short* Ab = (const unsigned short*)Agv;

  // staging addresses (pre-swizzled global sources)
  const int ar8 = t >> 3;                       // AF32: row in 64-row line
  const int ac8 = ((t & 7) ^ (ar8 & 7)) * 4;    // global f32 col
  const int ar4 = t >> 2;                       // bf16: row in 128-row line
  const int ac4 = ((t & 3) ^ (ar4 & 3)) * 8;    // global bf16 col
  const unsigned short* bS = Bg + (size_t)(col0 + ar4) * 512 + ac4;

  auto STAGE_A = [&](int kt) {
    if constexpr (AF32) {
      unsigned short* dst = &sm[(kt % 3) * 16384 + w * 512];
      const float* src = Af + (size_t)(row0 + ar8) * 512 + kt * 32 + ac8;
      #pragma unroll
      for (int i = 0; i < 4; ++i)
        gl_lds16((const unsigned short*)(src + (size_t)i * 64 * 512), dst + i * 4096);
    } else {
      unsigned short* dst = &sm[(kt % 3) * 8192 + w * 512];
      const unsigned short* src = Ab + (size_t)(row0 + ar4) * 512 + kt * 32 + ac4;
      gl_lds16(src, dst);
      gl_lds16(src + (size_t)128 * 512, dst + 4096);
    }
  };
  auto STAGE_B = [&](int kt) {
    unsigned short* dst = &smB[(kt % 3) * 8192 + w * 512];
    gl_lds16(bS + kt * 32, dst);
    gl_lds16(bS + (size_t)128 * 512 + kt * 32, dst + 4096);
  };

  f32x4 acc[8][4] = {};

  // prologue: stage tiles 0,1; wait tile0 (tile1 stays in flight)
  STAGE_A(0); STAGE_B(0); STAGE_A(1); STAGE_B(1);
  memfence_sched();
  if constexpr (AF32) asm volatile("s_waitcnt vmcnt(6)" ::: "memory");
  else                asm volatile("s_waitcnt vmcnt(4)" ::: "memory");
  __builtin_amdgcn_s_barrier();
  memfence_sched();

  #pragma unroll
  for (int kt = 0; kt < 16; ++kt) {
    if (kt <= 13) { STAGE_A(kt + 2); STAGE_B(kt + 2); }   // slot freed at bar kt-1
    memfence_sched();

    const unsigned short* aB = &sm[(kt % 3) * ASLOT];
    const unsigned short* bB = &smB[(kt % 3) * 8192];

    bf16x8 bfr[4], a0[4], a1[4];
    #pragma unroll
    for (int nj = 0; nj < 4; ++nj) {
      const int r = wn * 64 + nj * 16 + lo;               // r&3 == lo&3
      bfr[nj] = *reinterpret_cast<const bf16x8*>(&bB[r * 32 + ((hi ^ (lo & 3)) * 8)]);
    }
    if constexpr (AF32) {
      const float* afp = (const float*)aB;
      #pragma unroll
      for (int mi = 0; mi < 4; ++mi) {
        const int r = wm * 128 + mi * 16 + lo;            // r&7 == lo&7
        const float4 p = *reinterpret_cast<const float4*>(
            afp + r * 32 + (((2 * hi)     ^ (lo & 7)) * 4));
        const float4 q = *reinterpret_cast<const float4*>(
            afp + r * 32 + (((2 * hi + 1) ^ (lo & 7)) * 4));
        uint4 u;
        u.x = cvtpk(p.x, p.y); u.y = cvtpk(p.z, p.w);
        u.z = cvtpk(q.x, q.y); u.w = cvtpk(q.z, q.w);
        a0[mi] = __builtin_bit_cast(bf16x8, u);
      }
      #pragma unroll
      for (int mi = 0; mi < 4; ++mi) {
        const int r = wm * 128 + (mi + 4) * 16 + lo;
        const float4 p = *reinterpret_cast<const float4*>(
            afp + r * 32 + (((2 * hi)     ^ (lo & 7)) * 4));
        const float4 q = *reinterpret_cast<const float4*>(
            afp + r * 32 + (((2 * hi + 1) ^ (lo & 7)) * 4));
        uint4 u;
        u.x = cvtpk(p.x, p.y); u.y = cvtpk(p.z, p.w);
        u.z = cvtpk(q.x, q.y); u.w = cvtpk(q.z, q.w);
        a1[mi] = __builtin_bit_cast(bf16x8, u);
      }
    } else {
      #pragma unroll
      for (int mi = 0; mi < 4; ++mi) {
        const int r = wm * 128 + mi * 16 + lo;
        a0[mi] = *reinterpret_cast<const bf16x8*>(&aB[r * 32 + ((hi ^ (lo & 3)) * 8)]);
      }
      #pragma unroll
      for (int mi = 0; mi < 4; ++mi) {
        const int r = wm * 128 + (mi + 4) * 16 + lo;
        a1[mi] = *reinterpret_cast<const bf16x8*>(&aB[r * 32 + ((hi ^ (lo & 3)) * 8)]);
      }
    }
    asm volatile("s_waitcnt lgkmcnt(0)" ::: "memory");
    __builtin_amdgcn_sched_barrier(0);

    __builtin_amdgcn_s_setprio(1);
    #pragma unroll
    for (int mi = 0; mi < 4; ++mi)
      #pragma unroll
      for (int nj = 0; nj < 4; ++nj)
        acc[mi][nj] = mfma16(a0[mi], bfr[nj], acc[mi][nj]);
    #pragma unroll
    for (int mi = 0; mi < 4; ++mi)
      #pragma unroll
      for (int nj = 0; nj < 4; ++nj)
        acc[mi + 4][nj] = mfma16(a1[mi], bfr[nj], acc[mi + 4][nj]);
    __builtin_amdgcn_s_setprio(0);

    if (kt <= 13) {
      if constexpr (AF32) asm volatile("s_waitcnt vmcnt(6)" ::: "memory");  // kt+1 done
      else                asm volatile("s_waitcnt vmcnt(4)" ::: "memory");
    } else if (kt == 14) {
      asm volatile("s_waitcnt vmcnt(0)" ::: "memory");
    }
    if (kt < 15) { __builtin_amdgcn_s_barrier(); memfence_sched(); }
  }

  if constexpr (MODE == 3) {
    // fused kv epilogue; per-wave private 4096-ush bounce region
    __syncthreads();
    unsigned short* Tb = &sm[w * 4096];
    if (col0 < 512) {
      #pragma unroll
      for (int p = 0; p < 2; ++p) {
        #pragma unroll
        for (int q = 0; q < 4; ++q)
          #pragma unroll
          for (int nj = 0; nj < 4; ++nj)
            #pragma unroll
            for (int r = 0; r < 4; ++r)
              Tb[(q * 16 + hi * 4 + r) * 64 + nj * 16 + lo] = f2bf(acc[p * 4 + q][nj][r]);
        asm volatile("s_waitcnt lgkmcnt(0)" ::: "memory");
        #pragma unroll
        for (int it = 0; it < 8; ++it) {
          const int rr = it * 8 + (lane >> 3);
          const bf16x8 v = *reinterpret_cast<const bf16x8*>(&Tb[rr * 64 + (lane & 7) * 8]);
          const size_t gm = (size_t)row0 + wm * 128 + p * 64 + rr;
          *reinterpret_cast<bf16x8*>((unsigned short*)Cg + gm * 512 + col0 + wn * 64 +
                                     (lane & 7) * 8) = v;
        }
      }
    } else {
      #pragma unroll
      for (int p = 0; p < 2; ++p) {
        #pragma unroll
        for (int q = 0; q < 4; ++q)
          #pragma unroll
          for (int nj = 0; nj < 4; ++nj)
            #pragma unroll
            for (int r = 0; r < 4; ++r) {
              const int gn_l = nj * 16 + lo;
              const int gm_l = (q * 16 + hi * 4 + r) ^ ((gn_l & 15) * 4);
              Tb[gn_l * 64 + gm_l] = f2bf(acc[p * 4 + q][nj][r]);
            }
        asm volatile("s_waitcnt lgkmcnt(0)" ::: "memory");
        #pragma unroll
        for (int it = 0; it < 16; ++it) {
          const int gn_l = it * 4 + (lane >> 4);
          const int g4 = ((lane & 15) * 4) ^ ((gn_l & 15) * 4);
          const ush4 v = *reinterpret_cast<const ush4*>(&Tb[gn_l * 64 + g4]);
          const size_t vrow = (size_t)(col0 - 512) + wn * 64 + gn_l;
          const size_t vcol = (size_t)row0 + wm * 128 + p * 64 + (lane & 15) * 4;
          *reinterpret_cast<ush4*>((unsigned short*)Cg2 + vrow * 131072 + vcol) = v;
        }
        __builtin_amdgcn_s_barrier();
      }
    }
  } else {
    #pragma unroll
    for (int mi = 0; mi < 8; ++mi) {
      #pragma unroll
      for (int r = 0; r < 4; ++r) {
        const size_t gm = (size_t)row0 + wm * 128 + mi * 16 + hi * 4 + r;
        #pragma unroll
        for (int nj = 0; nj < 4; ++nj) {
          const int gn = col0 + wn * 64 + nj * 16 + lo;
          const float v = acc[mi][nj][r];
          if constexpr (MODE == 0)
            ((unsigned short*)Cg)[gm * ldc + gn] = f2bf(v * 0.125f);
          else
            ((float*)Cg)[gm * ldc + gn] = v + bias[gn];
        }
      }
    }
  }
}

// Flash attention, KV split 4-way: grid = 2048 (b,h,qhalf,chunk), 256 thr
// (4 waves x 16 q-rows). Writes partials (o fp32, m, l) for combine pass.
// k [131072, 512] bf16 (col h*64+d); vT [512, 131072] bf16.
__global__ __launch_bounds__(256)
void attn_fwd(const unsigned short* __restrict__ qh,
              const unsigned short* __restrict__ kbuf,
              const unsigned short* __restrict__ vT,
              const float* __restrict__ mask,
              float* __restrict__ opart, float* __restrict__ ml)
{
  __shared__ unsigned short Ks[64 * 64];
  __shared__ unsigned short Vs[64 * 64];
  __shared__ unsigned short Ps[4][16 * 64];
  const int bid = blockIdx.x;
  const int xcd = bid & 7, g = bid >> 3;
  const int b = (g >> 6) * 8 + xcd;
  const int sub = g & 63;
  const int h = sub >> 3, qhalf = (sub >> 2) & 1, c = sub & 3;
  const int n0 = c * 1024;
  const int bh2 = (b * 8 + h) * 2 + qhalf;
  const int t = threadIdx.x, lane = t & 63, w = t >> 6;
  const int hi = lane >> 4, lo = lane & 15;
  const int q0 = qhalf * 64 + w * 16;

  bf16x8 aq[2];
  #pragma unroll
  for (int kk = 0; kk < 2; ++kk)
    aq[kk] = *reinterpret_cast<const bf16x8*>(
        qh + (size_t)(b * 128 + q0 + lo) * 512 + h * 64 + kk * 32 + hi * 8);

  float mrow[4], lrow[4];
  #pragma unroll
  for (int i = 0; i < 4; ++i) { mrow[i] = -1e30f; lrow[i] = 0.f; }
  f32x4 o[4] = {};

  const unsigned short* kp = kbuf + ((size_t)b * 4096 + n0) * 512 + h * 64;
  const unsigned short* vp = vT + (size_t)(h * 64) * 131072 + (size_t)b * 4096 + n0;
  const float* mp = mask + ((size_t)(b * 128 + q0)) * 4096 + n0;

  for (int nt = 0; nt < 16; ++nt) {
    {
      const int r = t >> 3, cc = t & 7;
      *reinterpret_cast<uint4*>(&Ks[r * 64 + ((cc ^ (r & 7)) << 3)]) =
          *reinterpret_cast<const uint4*>(kp + (size_t)(nt * 64 + r) * 512 + (cc << 3));
      *reinterpret_cast<uint4*>(&Ks[(r + 32) * 64 + ((cc ^ (r & 7)) << 3)]) =
          *reinterpret_cast<const uint4*>(kp + (size_t)(nt * 64 + r + 32) * 512 + (cc << 3));
      *reinterpret_cast<uint4*>(&Vs[r * 64 + ((cc ^ (r & 7)) << 3)]) =
          *reinterpret_cast<const uint4*>(vp + (size_t)r * 131072 + nt * 64 + (cc << 3));
      *reinterpret_cast<uint4*>(&Vs[(r + 32) * 64 + ((cc ^ (r & 7)) << 3)]) =
          *reinterpret_cast<const uint4*>(vp + (size_t)(r + 32) * 131072 + nt * 64 + (cc << 3));
    }
    __syncthreads();

    f32x4 s[4] = {};
    __builtin_amdgcn_s_setprio(1);
    #pragma unroll
    for (int ni = 0; ni < 4; ++ni) {
      #pragma unroll
      for (int kk = 0; kk < 2; ++kk) {
        const bf16x8 kf = *reinterpret_cast<const bf16x8*>(
            &Ks[(ni * 16 + lo) * 64 + ((kk * 32 + hi * 8) ^ ((lo & 7) << 3))]);
        s[ni] = mfma16(aq[kk], kf, s[ni]);
      }
    }
    __builtin_amdgcn_s_setprio(0);
    #pragma unroll
    for (int ni = 0; ni < 4; ++ni)
      #pragma unroll
      for (int r = 0; r < 4; ++r)
        s[ni][r] += mp[(size_t)(hi * 4 + r) * 4096 + nt * 64 + ni * 16 + lo];

    #pragma unroll
    for (int r = 0; r < 4; ++r) {
      float mx = fmaxf(fmaxf(s[0][r], s[1][r]), fmaxf(s[2][r], s[3][r]));
      #pragma unroll
      for (int off = 1; off < 16; off <<= 1)
        mx = fmaxf(mx, __shfl_xor(mx, off, 64));
      const float mnew = fmaxf(mrow[r], mx);
      const float corr = __expf(mrow[r] - mnew);
      mrow[r] = mnew;
      float ls = 0.f;
      #pragma unroll
      for (int ni = 0; ni < 4; ++ni) {
        const float p = __expf(s[ni][r] - mnew);
        s[ni][r] = p; ls += p;
      }
      #pragma unroll
      for (int off = 1; off < 16; off <<= 1)
        ls += __shfl_xor(ls, off, 64);
      lrow[r] = lrow[r] * corr + ls;
      #pragma unroll
      for (int di = 0; di < 4; ++di)
        o[di][r] *= corr;
    }

    #pragma unroll
    for (int ni = 0; ni < 4; ++ni)
      #pragma unroll
      for (int r = 0; r < 4; ++r) {
        const int rp = hi * 4 + r;
        Ps[w][rp * 64 + ((ni * 16 + lo) ^ ((rp & 7) << 3))] = f2bf(s[ni][r]);
      }

    __builtin_amdgcn_s_setprio(1);
    #pragma unroll
    for (int kk = 0; kk < 2; ++kk) {
      const bf16x8 pa = *reinterpret_cast<const bf16x8*>(
          &Ps[w][lo * 64 + ((kk * 32 + hi * 8) ^ ((lo & 7) << 3))]);
      #pragma unroll
      for (int di = 0; di < 4; ++di) {
        const bf16x8 vf = *reinterpret_cast<const bf16x8*>(
            &Vs[(di * 16 + lo) * 64 + ((kk * 32 + hi * 8) ^ ((lo & 7) << 3))]);
        o[di] = mfma16(pa, vf, o[di]);
      }
    }
    __builtin_amdgcn_s_setprio(0);
    __syncthreads();
  }

  const size_t pbase = ((size_t)bh2 * 4 + c) * 64;
  #pragma unroll
  for (int di = 0; di < 4; ++di)
    #pragma unroll
    for (int r = 0; r < 4; ++r)
      opart[(pbase + (w * 16 + hi * 4 + r)) * 64 + di * 16 + lo] = o[di][r];
  if (lo == 0) {
    #pragma unroll
    for (int r = 0; r < 4; ++r) {
      const int qq = w * 16 + hi * 4 + r;
      ml[(((size_t)bh2 * 4 + c) * 2 + 0) * 64 + qq] = mrow[r];
      ml[(((size_t)bh2 * 4 + c) * 2 + 1) * 64 + qq] = lrow[r];
    }
  }
}

// Combine 4 chunk-partials -> xb bf16. grid = 512 (bh2), 256 thr.
__global__ __launch_bounds__(256)
void attn_combine(const float* __restrict__ opart, const float* __restrict__ ml,
                  unsigned short* __restrict__ xb)
{
  const int bh2 = blockIdx.x;
  const int b = bh2 >> 4, h = (bh2 >> 1) & 7, qhalf = bh2 & 1;
  const int t = threadIdx.x;
  const int q = t >> 2, dg = t & 3;

  float m[4], l[4];
  #pragma unroll
  for (int c = 0; c < 4; ++c) {
    m[c] = ml[(((size_t)bh2 * 4 + c) * 2 + 0) * 64 + q];
    l[c] = ml[(((size_t)bh2 * 4 + c) * 2 + 1) * 64 + q];
  }
  const float M = fmaxf(fmaxf(m[0], m[1]), fmaxf(m[2], m[3]));
  float sc[4], L = 0.f;
  #pragma unroll
  for (int c = 0; c < 4; ++c) { sc[c] = __expf(m[c] - M); L += sc[c] * l[c]; }
  const float inv = 1.f / L;

  float4 acc[4] = {};
  #pragma unroll
  for (int c = 0; c < 4; ++c) {
    const float* base = opart + (((size_t)bh2 * 4 + c) * 64 + q) * 64 + dg * 16;
    #pragma unroll
    for (int j = 0; j < 4; ++j) {
      const float4 v = *reinterpret_cast<const float4*>(base + j * 4);
      acc[j].x = fmaf(sc[c], v.x, acc[j].x);
      acc[j].y = fmaf(sc[c], v.y, acc[j].y);
      acc[j].z = fmaf(sc[c], v.z, acc[j].z);
      acc[j].w = fmaf(sc[c], v.w, acc[j].w);
    }
  }
  unsigned short* dst = xb + ((size_t)b * 128 + qhalf * 64 + q) * 512 + h * 64 + dg * 16;
  uint4 o1, o2;
  o1.x = cvtpk(acc[0].x * inv, acc[0].y * inv); o1.y = cvtpk(acc[0].z * inv, acc[0].w * inv);
  o1.z = cvtpk(acc[1].x * inv, acc[1].y * inv); o1.w = cvtpk(acc[1].z * inv, acc[1].w * inv);
  o2.x = cvtpk(acc[2].x * inv, acc[2].y * inv); o2.y = cvtpk(acc[2].z * inv, acc[2].w * inv);
  o2.z = cvtpk(acc[3].x * inv, acc[3].y * inv); o2.w = cvtpk(acc[3].z * inv, acc[3].w * inv);
  *reinterpret_cast<uint4*>(dst) = o1;
  *reinterpret_cast<uint4*>(dst + 8) = o2;
}

extern "C" void kernel_launch(void* const* d_in, const int* in_sizes, int n_in,
                              void* d_out, int out_size, void* d_ws, size_t ws_size,
                              hipStream_t stream) {
  const float* q     = (const float*)d_in[0];
  const float* kv    = (const float*)d_in[1];
  const float* mask  = (const float*)d_in[2];
  const float* Wq    = (const float*)d_in[3];
  const float* Wkv   = (const float*)d_in[4];
  const float* Wproj = (const float*)d_in[5];
  const float* bproj = (const float*)d_in[6];
  float* out = (float*)d_out;

  char* ws = (char*)d_ws;
  unsigned short* kbuf   = (unsigned short*)ws;                      // 134.2 MB [131072,512]
  unsigned short* vTb    = (unsigned short*)(ws + 134217728ULL);     // 134.2 MB [512,131072]
  float*          opart  = (float*)(ws + 268435456ULL);              // 33.6 MB [512][4][64][64]
  float*          mlb    = (float*)(ws + 301989888ULL);              // 1.0 MB
  unsigned short* qhb    = (unsigned short*)(ws + 303038464ULL);     // 4.2 MB
  unsigned short* xb     = (unsigned short*)(ws + 307232768ULL);     // 4.2 MB
  unsigned short* Wqb    = (unsigned short*)(ws + 311427072ULL);     // 0.5 MB
  unsigned short* Wkvb   = (unsigned short*)(ws + 311951360ULL);     // 1.0 MB
  unsigned short* Wprojb = (unsigned short*)(ws + 312999936ULL);     // 0.5 MB

  cvt_f32_bf16<<<128, 256, 0, stream>>>(Wq, Wqb, 512 * 512 / 8);
  cvt_f32_bf16<<<256, 256, 0, stream>>>(Wkv, Wkvb, 1024 * 512 / 8);
  cvt_f32_bf16<<<128, 256, 0, stream>>>(Wproj, Wprojb, 512 * 512 / 8);

  // qh = (q @ Wq^T) * scale        M=4096, N=512  (A fp32 in LDS)
  gemmF<0, true><<<32, 512, 0, stream>>>(q, Wqb, qhb, nullptr, nullptr, 2, 512);
  // fused kv projection: k + vT in one pass over kv fp32
  gemmF<3, true><<<2048, 512, 0, stream>>>(kv, Wkvb, kbuf, vTb, nullptr, 4, 512);
  // flash attention partials
  attn_fwd<<<2048, 256, 0, stream>>>(qhb, kbuf, vTb, mask, opart, mlb);
  // combine -> xb bf16
  attn_combine<<<512, 256, 0, stream>>>(opart, mlb, xb);
  // out = x @ Wproj^T + bproj
  gemmF<2, false><<<32, 512, 0, stream>>>(xb, Wprojb, out, nullptr, bproj, 2, 512);
}

// Round 13
// 420.398 us; speedup vs baseline: 1.1645x; 1.1645x over previous
//
#include <hip/hip_runtime.h>
#include <hip/hip_bf16.h>

typedef __attribute__((ext_vector_type(4))) float f32x4;
typedef __attribute__((ext_vector_type(8))) short bf16x8;
typedef __attribute__((ext_vector_type(4))) unsigned short ush4;

#define GAS __attribute__((address_space(1)))
#define LAS __attribute__((address_space(3)))

__device__ __forceinline__ unsigned int cvtpk(float lo, float hi) {
  unsigned int r;
  asm("v_cvt_pk_bf16_f32 %0, %1, %2" : "=v"(r) : "v"(lo), "v"(hi));
  return r;
}
__device__ __forceinline__ unsigned short f2bf(float f) { return (unsigned short)cvtpk(f, f); }
__device__ __forceinline__ f32x4 mfma16(bf16x8 a, bf16x8 b, f32x4 c) {
  return __builtin_amdgcn_mfma_f32_16x16x32_bf16(a, b, c, 0, 0, 0);
}
__device__ __forceinline__ void gl_lds16(const unsigned short* g, unsigned short* l) {
  __builtin_amdgcn_global_load_lds((const GAS unsigned short*)g, (LAS unsigned short*)l, 16, 0, 0);
}
__device__ __forceinline__ void memfence_sched() { asm volatile("" ::: "memory"); }

__global__ __launch_bounds__(256)
void cvt_f32_bf16(const float* __restrict__ in, unsigned short* __restrict__ out, int n8) {
  for (int i = blockIdx.x * blockDim.x + threadIdx.x; i < n8; i += gridDim.x * blockDim.x) {
    const float4 a = *reinterpret_cast<const float4*>(in + (size_t)i * 8);
    const float4 b = *reinterpret_cast<const float4*>(in + (size_t)i * 8 + 4);
    uint4 o;
    o.x = cvtpk(a.x, a.y); o.y = cvtpk(a.z, a.w);
    o.z = cvtpk(b.x, b.y); o.w = cvtpk(b.z, b.w);
    *reinterpret_cast<uint4*>(out + (size_t)i * 8) = o;
  }
}

// C[M,N] = A[M,512] @ B[N,512]^T.  128x128 tile, BK=32, 16 K-steps,
// 256 thr (4 waves 2x2), per-wave 64x64 (acc[4][4] = 64 AGPRs -> 3 waves/SIMD,
// ~3 blocks/CU: inter-block overlap hides barrier drains — m97/m114 recipe).
// MIXED (AF32): A fp32 reg-staged depth-2 + cvt_pk + swizzled ds_write
// (2 LDS slots); B bf16 global_load_lds depth-1 (2 slots, pre-swizzled src).
// Pure: both via gl_lds, depth-1, vmcnt(0) at step end (used only for tiny out-GEMM).
// LDS 32 KB. Swizzle key (row>>1)&3 on 16B chunks (round-6 scheme: measured
// SQ_LDS_BANK_CONFLICT = 0). Waits (MIXED): mid vmcnt(6) -> F_WRITE(kt+1);
// end vmcnt(4) -> G(kt+1) landed; tail 2 -> 0 (counted, T4).
// MODE 0: bf16 out *0.125 ; MODE 2: f32 out + bias ;
// MODE 3: fused kv epilogue — col0<512 -> k rows ; col0>=512 -> vT transpose.
template<int MODE, bool AF32>
__global__ __launch_bounds__(256, 3)
void gemmM(const void* __restrict__ Agv, const unsigned short* __restrict__ Bg,
           void* __restrict__ Cg, void* __restrict__ Cg2,
           const float* __restrict__ bias, int ntn, size_t ldc)
{
  __shared__ unsigned short sm[16384];   // A: (kt&1)*4096 ; B: 8192 + (kt&1)*4096
  unsigned short* const smB = sm + 8192;

  const int t = threadIdx.x, lane = t & 63, w = t >> 6;
  const int lo = lane & 15, hi = lane >> 4;
  const int wm = w >> 1, wn = w & 1;
  const int nwg = gridDim.x, bid = blockIdx.x;
  const int id = (bid & 7) * (nwg >> 3) + (bid >> 3);   // XCD swizzle (nwg%8==0)
  const int row0 = (id / ntn) * 128, col0 = (id % ntn) * 128;

  const float* Af = (const float*)Agv;
  const unsigned short* Ab = (const unsigned short*)Agv;

  // gl_lds addressing (pre-swizzled source): row w*32+i*16+(lane>>2),
  // LDS chunk lane&3, global chunk (lane&3)^((lane>>3)&3)
  const int swcol = ((lane & 3) ^ ((lane >> 3) & 3)) * 8;
  const unsigned short* bS = Bg + (size_t)(col0 + w * 32 + (lane >> 2)) * 512 + swcol;
  const unsigned short* aSg = Ab + (size_t)(row0 + w * 32 + (lane >> 2)) * 512 + swcol;

  // fp32 reg-staged addressing: rows t>>2 and t>>2 + 64, cols (t&3)*8..+7
  const int rs_r = t >> 2;
  const int rs_c = (t & 3) * 8;
  const int wch = ((t & 3) ^ ((t >> 3) & 3)) * 8;   // swizzled ds_write chunk

  float4 stF[2][4];

  auto F_ISSUE = [&](int kt) {
    if constexpr (AF32) {
      const int bk = kt & 1;
      const float* s0 = Af + (size_t)(row0 + rs_r) * 512 + kt * 32 + rs_c;
      const float* s1 = Af + (size_t)(row0 + 64 + rs_r) * 512 + kt * 32 + rs_c;
      stF[bk][0] = *(const float4*)s0; stF[bk][1] = *(const float4*)(s0 + 4);
      stF[bk][2] = *(const float4*)s1; stF[bk][3] = *(const float4*)(s1 + 4);
    }
  };
  auto F_WRITE = [&](int kt) {
    if constexpr (AF32) {
      const int bk = kt & 1;
      unsigned short* fb = &sm[(kt & 1) * 4096];
      uint4 o;
      o.x = cvtpk(stF[bk][0].x, stF[bk][0].y); o.y = cvtpk(stF[bk][0].z, stF[bk][0].w);
      o.z = cvtpk(stF[bk][1].x, stF[bk][1].y); o.w = cvtpk(stF[bk][1].z, stF[bk][1].w);
      *reinterpret_cast<uint4*>(&fb[rs_r * 32 + wch]) = o;
      o.x = cvtpk(stF[bk][2].x, stF[bk][2].y); o.y = cvtpk(stF[bk][2].z, stF[bk][2].w);
      o.z = cvtpk(stF[bk][3].x, stF[bk][3].y); o.w = cvtpk(stF[bk][3].z, stF[bk][3].w);
      *reinterpret_cast<uint4*>(&fb[(64 + rs_r) * 32 + wch]) = o;
    }
  };
  auto G_ISSUE = [&](int kt) {
    unsigned short* bb = &smB[(kt & 1) * 4096];
    gl_lds16(bS + kt * 32,                     bb + (w * 2 + 0) * 512);
    gl_lds16(bS + (size_t)16 * 512 + kt * 32,  bb + (w * 2 + 1) * 512);
    if constexpr (!AF32) {
      unsigned short* ab = &sm[(kt & 1) * 4096];
      gl_lds16(aSg + kt * 32,                    ab + (w * 2 + 0) * 512);
      gl_lds16(aSg + (size_t)16 * 512 + kt * 32, ab + (w * 2 + 1) * 512);
    }
  };

  f32x4 acc[4][4] = {};
  const int fxor = (hi ^ ((lo >> 1) & 3)) * 8;

  // ---- prologue ----
  if constexpr (AF32) {
    F_ISSUE(0);          // 4
    G_ISSUE(0);          // +2
    F_ISSUE(1);          // +4 -> 10
    memfence_sched();
    asm volatile("s_waitcnt vmcnt(6)" ::: "memory");   // F(0) done
    F_WRITE(0);
    asm volatile("s_waitcnt vmcnt(4)" ::: "memory");   // G(0) done
  } else {
    G_ISSUE(0);
    memfence_sched();
    asm volatile("s_waitcnt vmcnt(0)" ::: "memory");
  }
  asm volatile("s_waitcnt lgkmcnt(0)" ::: "memory");
  __builtin_amdgcn_s_barrier();
  memfence_sched();

  // ---- main loop ----
  #pragma unroll
  for (int kt = 0; kt < 16; ++kt) {
    const unsigned short* ab = &sm[(kt & 1) * 4096];
    const unsigned short* bb = &smB[(kt & 1) * 4096];
    bf16x8 bfr[4], af[4];
    #pragma unroll
    for (int nj = 0; nj < 4; ++nj)
      bfr[nj] = *reinterpret_cast<const bf16x8*>(&bb[(wn * 64 + nj * 16 + lo) * 32 + fxor]);
    #pragma unroll
    for (int mi = 0; mi < 4; ++mi)
      af[mi] = *reinterpret_cast<const bf16x8*>(&ab[(wm * 64 + mi * 16 + lo) * 32 + fxor]);

    if (kt <= 14) G_ISSUE(kt + 1);
    if constexpr (AF32) { if (kt <= 13) F_ISSUE(kt + 2); }
    memfence_sched();

    __builtin_amdgcn_s_setprio(1);
    #pragma unroll
    for (int mi = 0; mi < 2; ++mi)
      #pragma unroll
      for (int nj = 0; nj < 4; ++nj)
        acc[mi][nj] = mfma16(af[mi], bfr[nj], acc[mi][nj]);
    __builtin_amdgcn_s_setprio(0);

    if constexpr (AF32) {
      if (kt <= 13)      { asm volatile("s_waitcnt vmcnt(6)" ::: "memory"); }
      else if (kt == 14) { asm volatile("s_waitcnt vmcnt(2)" ::: "memory"); }
      if (kt <= 14) F_WRITE(kt + 1);
    }

    __builtin_amdgcn_s_setprio(1);
    #pragma unroll
    for (int mi = 2; mi < 4; ++mi)
      #pragma unroll
      for (int nj = 0; nj < 4; ++nj)
        acc[mi][nj] = mfma16(af[mi], bfr[nj], acc[mi][nj]);
    __builtin_amdgcn_s_setprio(0);

    if (kt < 15) {
      if constexpr (AF32) {
        if (kt <= 13) { asm volatile("s_waitcnt vmcnt(4)" ::: "memory"); }
        else          { asm volatile("s_waitcnt vmcnt(0)" ::: "memory"); }
      } else {
        asm volatile("s_waitcnt vmcnt(0)" ::: "memory");
      }
      asm volatile("s_waitcnt lgkmcnt(0)" ::: "memory");
      __builtin_amdgcn_s_barrier();
      memfence_sched();
    }
  }

  if constexpr (MODE == 3) {
    // fused kv epilogue; per-wave private 4096-ush bounce region
    __syncthreads();
    unsigned short* Tb = &sm[w * 4096];
    if (col0 < 512) {
      // k-part: straight bounce [64 gm][64 gn]; b128 row stores
      #pragma unroll
      for (int q = 0; q < 4; ++q)
        #pragma unroll
        for (int nj = 0; nj < 4; ++nj)
          #pragma unroll
          for (int r = 0; r < 4; ++r)
            Tb[(q * 16 + hi * 4 + r) * 64 + nj * 16 + lo] = f2bf(acc[q][nj][r]);
      asm volatile("s_waitcnt lgkmcnt(0)" ::: "memory");
      #pragma unroll
      for (int it = 0; it < 8; ++it) {
        const int rr = it * 8 + (lane >> 3);
        const bf16x8 v = *reinterpret_cast<const bf16x8*>(&Tb[rr * 64 + (lane & 7) * 8]);
        const size_t gm = (size_t)row0 + wm * 64 + rr;
        *reinterpret_cast<bf16x8*>((unsigned short*)Cg + gm * 512 + col0 + wn * 64 +
                                   (lane & 7) * 8) = v;
      }
    } else {
      // v-part: transpose bounce [64 gn][64 gm], row-keyed xor gm^=(gn&15)*4
      #pragma unroll
      for (int q = 0; q < 4; ++q)
        #pragma unroll
        for (int nj = 0; nj < 4; ++nj)
          #pragma unroll
          for (int r = 0; r < 4; ++r) {
            const int gn_l = nj * 16 + lo;
            const int gm_l = (q * 16 + hi * 4 + r) ^ ((gn_l & 15) * 4);
            Tb[gn_l * 64 + gm_l] = f2bf(acc[q][nj][r]);
          }
      asm volatile("s_waitcnt lgkmcnt(0)" ::: "memory");
      #pragma unroll
      for (int it = 0; it < 16; ++it) {
        const int gn_l = it * 4 + (lane >> 4);
        const int g4 = ((lane & 15) * 4) ^ ((gn_l & 15) * 4);
        const ush4 v = *reinterpret_cast<const ush4*>(&Tb[gn_l * 64 + g4]);
        const size_t vrow = (size_t)(col0 - 512) + wn * 64 + gn_l;
        const size_t vcol = (size_t)row0 + wm * 64 + (lane & 15) * 4;
        *reinterpret_cast<ush4*>((unsigned short*)Cg2 + vrow * 131072 + vcol) = v;
      }
    }
  } else {
    #pragma unroll
    for (int mi = 0; mi < 4; ++mi) {
      #pragma unroll
      for (int r = 0; r < 4; ++r) {
        const size_t gm = (size_t)row0 + wm * 64 + mi * 16 + hi * 4 + r;
        #pragma unroll
        for (int nj = 0; nj < 4; ++nj) {
          const int gn = col0 + wn * 64 + nj * 16 + lo;
          const float v = acc[mi][nj][r];
          if constexpr (MODE == 0)
            ((unsigned short*)Cg)[gm * ldc + gn] = f2bf(v * 0.125f);
          else
            ((float*)Cg)[gm * ldc + gn] = v + bias[gn];
        }
      }
    }
  }
}

// Flash attention, KV split 4-way: grid = 2048 (b,h,qhalf,chunk), 256 thr
// (4 waves x 16 q-rows). Writes partials (o fp32, m, l) for combine pass.
// k [131072, 512] bf16 (col h*64+d); vT [512, 131072] bf16.
__global__ __launch_bounds__(256)
void attn_fwd(const unsigned short* __restrict__ qh,
              const unsigned short* __restrict__ kbuf,
              const unsigned short* __restrict__ vT,
              const float* __restrict__ mask,
              float* __restrict__ opart, float* __restrict__ ml)
{
  __shared__ unsigned short Ks[64 * 64];
  __shared__ unsigned short Vs[64 * 64];
  __shared__ unsigned short Ps[4][16 * 64];
  const int bid = blockIdx.x;
  const int xcd = bid & 7, g = bid >> 3;
  const int b = (g >> 6) * 8 + xcd;
  const int sub = g & 63;
  const int h = sub >> 3, qhalf = (sub >> 2) & 1, c = sub & 3;
  const int n0 = c * 1024;
  const int bh2 = (b * 8 + h) * 2 + qhalf;
  const int t = threadIdx.x, lane = t & 63, w = t >> 6;
  const int hi = lane >> 4, lo = lane & 15;
  const int q0 = qhalf * 64 + w * 16;

  bf16x8 aq[2];
  #pragma unroll
  for (int kk = 0; kk < 2; ++kk)
    aq[kk] = *reinterpret_cast<const bf16x8*>(
        qh + (size_t)(b * 128 + q0 + lo) * 512 + h * 64 + kk * 32 + hi * 8);

  float mrow[4], lrow[4];
  #pragma unroll
  for (int i = 0; i < 4; ++i) { mrow[i] = -1e30f; lrow[i] = 0.f; }
  f32x4 o[4] = {};

  const unsigned short* kp = kbuf + ((size_t)b * 4096 + n0) * 512 + h * 64;
  const unsigned short* vp = vT + (size_t)(h * 64) * 131072 + (size_t)b * 4096 + n0;
  const float* mp = mask + ((size_t)(b * 128 + q0)) * 4096 + n0;

  for (int nt = 0; nt < 16; ++nt) {
    {
      const int r = t >> 3, cc = t & 7;
      *reinterpret_cast<uint4*>(&Ks[r * 64 + ((cc ^ (r & 7)) << 3)]) =
          *reinterpret_cast<const uint4*>(kp + (size_t)(nt * 64 + r) * 512 + (cc << 3));
      *reinterpret_cast<uint4*>(&Ks[(r + 32) * 64 + ((cc ^ (r & 7)) << 3)]) =
          *reinterpret_cast<const uint4*>(kp + (size_t)(nt * 64 + r + 32) * 512 + (cc << 3));
      *reinterpret_cast<uint4*>(&Vs[r * 64 + ((cc ^ (r & 7)) << 3)]) =
          *reinterpret_cast<const uint4*>(vp + (size_t)r * 131072 + nt * 64 + (cc << 3));
      *reinterpret_cast<uint4*>(&Vs[(r + 32) * 64 + ((cc ^ (r & 7)) << 3)]) =
          *reinterpret_cast<const uint4*>(vp + (size_t)(r + 32) * 131072 + nt * 64 + (cc << 3));
    }
    __syncthreads();

    f32x4 s[4] = {};
    __builtin_amdgcn_s_setprio(1);
    #pragma unroll
    for (int ni = 0; ni < 4; ++ni) {
      #pragma unroll
      for (int kk = 0; kk < 2; ++kk) {
        const bf16x8 kf = *reinterpret_cast<const bf16x8*>(
            &Ks[(ni * 16 + lo) * 64 + ((kk * 32 + hi * 8) ^ ((lo & 7) << 3))]);
        s[ni] = mfma16(aq[kk], kf, s[ni]);
      }
    }
    __builtin_amdgcn_s_setprio(0);
    #pragma unroll
    for (int ni = 0; ni < 4; ++ni)
      #pragma unroll
      for (int r = 0; r < 4; ++r)
        s[ni][r] += mp[(size_t)(hi * 4 + r) * 4096 + nt * 64 + ni * 16 + lo];

    #pragma unroll
    for (int r = 0; r < 4; ++r) {
      float mx = fmaxf(fmaxf(s[0][r], s[1][r]), fmaxf(s[2][r], s[3][r]));
      #pragma unroll
      for (int off = 1; off < 16; off <<= 1)
        mx = fmaxf(mx, __shfl_xor(mx, off, 64));
      const float mnew = fmaxf(mrow[r], mx);
      const float corr = __expf(mrow[r] - mnew);
      mrow[r] = mnew;
      float ls = 0.f;
      #pragma unroll
      for (int ni = 0; ni < 4; ++ni) {
        const float p = __expf(s[ni][r] - mnew);
        s[ni][r] = p; ls += p;
      }
      #pragma unroll
      for (int off = 1; off < 16; off <<= 1)
        ls += __shfl_xor(ls, off, 64);
      lrow[r] = lrow[r] * corr + ls;
      #pragma unroll
      for (int di = 0; di < 4; ++di)
        o[di][r] *= corr;
    }

    #pragma unroll
    for (int ni = 0; ni < 4; ++ni)
      #pragma unroll
      for (int r = 0; r < 4; ++r) {
        const int rp = hi * 4 + r;
        Ps[w][rp * 64 + ((ni * 16 + lo) ^ ((rp & 7) << 3))] = f2bf(s[ni][r]);
      }

    __builtin_amdgcn_s_setprio(1);
    #pragma unroll
    for (int kk = 0; kk < 2; ++kk) {
      const bf16x8 pa = *reinterpret_cast<const bf16x8*>(
          &Ps[w][lo * 64 + ((kk * 32 + hi * 8) ^ ((lo & 7) << 3))]);
      #pragma unroll
      for (int di = 0; di < 4; ++di) {
        const bf16x8 vf = *reinterpret_cast<const bf16x8*>(
            &Vs[(di * 16 + lo) * 64 + ((kk * 32 + hi * 8) ^ ((lo & 7) << 3))]);
        o[di] = mfma16(pa, vf, o[di]);
      }
    }
    __builtin_amdgcn_s_setprio(0);
    __syncthreads();
  }

  const size_t pbase = ((size_t)bh2 * 4 + c) * 64;
  #pragma unroll
  for (int di = 0; di < 4; ++di)
    #pragma unroll
    for (int r = 0; r < 4; ++r)
      opart[(pbase + (w * 16 + hi * 4 + r)) * 64 + di * 16 + lo] = o[di][r];
  if (lo == 0) {
    #pragma unroll
    for (int r = 0; r < 4; ++r) {
      const int qq = w * 16 + hi * 4 + r;
      ml[(((size_t)bh2 * 4 + c) * 2 + 0) * 64 + qq] = mrow[r];
      ml[(((size_t)bh2 * 4 + c) * 2 + 1) * 64 + qq] = lrow[r];
    }
  }
}

// Combine 4 chunk-partials -> xb bf16. grid = 512 (bh2), 256 thr.
__global__ __launch_bounds__(256)
void attn_combine(const float* __restrict__ opart, const float* __restrict__ ml,
                  unsigned short* __restrict__ xb)
{
  const int bh2 = blockIdx.x;
  const int b = bh2 >> 4, h = (bh2 >> 1) & 7, qhalf = bh2 & 1;
  const int t = threadIdx.x;
  const int q = t >> 2, dg = t & 3;

  float m[4], l[4];
  #pragma unroll
  for (int c = 0; c < 4; ++c) {
    m[c] = ml[(((size_t)bh2 * 4 + c) * 2 + 0) * 64 + q];
    l[c] = ml[(((size_t)bh2 * 4 + c) * 2 + 1) * 64 + q];
  }
  const float M = fmaxf(fmaxf(m[0], m[1]), fmaxf(m[2], m[3]));
  float sc[4], L = 0.f;
  #pragma unroll
  for (int c = 0; c < 4; ++c) { sc[c] = __expf(m[c] - M); L += sc[c] * l[c]; }
  const float inv = 1.f / L;

  float4 acc[4] = {};
  #pragma unroll
  for (int c = 0; c < 4; ++c) {
    const float* base = opart + (((size_t)bh2 * 4 + c) * 64 + q) * 64 + dg * 16;
    #pragma unroll
    for (int j = 0; j < 4; ++j) {
      const float4 v = *reinterpret_cast<const float4*>(base + j * 4);
      acc[j].x = fmaf(sc[c], v.x, acc[j].x);
      acc[j].y = fmaf(sc[c], v.y, acc[j].y);
      acc[j].z = fmaf(sc[c], v.z, acc[j].z);
      acc[j].w = fmaf(sc[c], v.w, acc[j].w);
    }
  }
  unsigned short* dst = xb + ((size_t)b * 128 + qhalf * 64 + q) * 512 + h * 64 + dg * 16;
  uint4 o1, o2;
  o1.x = cvtpk(acc[0].x * inv, acc[0].y * inv); o1.y = cvtpk(acc[0].z * inv, acc[0].w * inv);
  o1.z = cvtpk(acc[1].x * inv, acc[1].y * inv); o1.w = cvtpk(acc[1].z * inv, acc[1].w * inv);
  o2.x = cvtpk(acc[2].x * inv, acc[2].y * inv); o2.y = cvtpk(acc[2].z * inv, acc[2].w * inv);
  o2.z = cvtpk(acc[3].x * inv, acc[3].y * inv); o2.w = cvtpk(acc[3].z * inv, acc[3].w * inv);
  *reinterpret_cast<uint4*>(dst) = o1;
  *reinterpret_cast<uint4*>(dst + 8) = o2;
}

extern "C" void kernel_launch(void* const* d_in, const int* in_sizes, int n_in,
                              void* d_out, int out_size, void* d_ws, size_t ws_size,
                              hipStream_t stream) {
  const float* q     = (const float*)d_in[0];
  const float* kv    = (const float*)d_in[1];
  const float* mask  = (const float*)d_in[2];
  const float* Wq    = (const float*)d_in[3];
  const float* Wkv   = (const float*)d_in[4];
  const float* Wproj = (const float*)d_in[5];
  const float* bproj = (const float*)d_in[6];
  float* out = (float*)d_out;

  char* ws = (char*)d_ws;
  unsigned short* kbuf   = (unsigned short*)ws;                      // 134.2 MB [131072,512]
  unsigned short* vTb    = (unsigned short*)(ws + 134217728ULL);     // 134.2 MB [512,131072]
  float*          opart  = (float*)(ws + 268435456ULL);              // 33.6 MB [512][4][64][64]
  float*          mlb    = (float*)(ws + 301989888ULL);              // 1.0 MB
  unsigned short* qhb    = (unsigned short*)(ws + 303038464ULL);     // 4.2 MB
  unsigned short* xb     = (unsigned short*)(ws + 307232768ULL);     // 4.2 MB
  unsigned short* Wqb    = (unsigned short*)(ws + 311427072ULL);     // 0.5 MB
  unsigned short* Wkvb   = (unsigned short*)(ws + 311951360ULL);     // 1.0 MB
  unsigned short* Wprojb = (unsigned short*)(ws + 312999936ULL);     // 0.5 MB

  cvt_f32_bf16<<<128, 256, 0, stream>>>(Wq, Wqb, 512 * 512 / 8);
  cvt_f32_bf16<<<256, 256, 0, stream>>>(Wkv, Wkvb, 1024 * 512 / 8);
  cvt_f32_bf16<<<128, 256, 0, stream>>>(Wproj, Wprojb, 512 * 512 / 8);

  // qh = (q @ Wq^T) * scale        M=4096, N=512  (A fp32, MIXED)
  gemmM<0, true><<<128, 256, 0, stream>>>(q, Wqb, qhb, nullptr, nullptr, 4, 512);
  // fused kv projection: k + vT in one pass over kv fp32 (MIXED)
  gemmM<3, true><<<8192, 256, 0, stream>>>(kv, Wkvb, kbuf, vTb, nullptr, 8, 512);
  // flash attention partials
  attn_fwd<<<2048, 256, 0, stream>>>(qhb, kbuf, vTb, mask, opart, mlb);
  // combine -> xb bf16
  attn_combine<<<512, 256, 0, stream>>>(opart, mlb, xb);
  // out = x @ Wproj^T + bproj     (pure bf16)
  gemmM<2, false><<<128, 256, 0, stream>>>(xb, Wprojb, out, nullptr, bproj, 4, 512);
}

// Round 14
// 395.938 us; speedup vs baseline: 1.2364x; 1.0618x over previous
//
#include <hip/hip_runtime.h>
#include <hip/hip_bf16.h>

typedef __attribute__((ext_vector_type(4))) float f32x4;
typedef __attribute__((ext_vector_type(8))) short bf16x8;
typedef __attribute__((ext_vector_type(4))) unsigned short ush4;

#define GAS __attribute__((address_space(1)))
#define LAS __attribute__((address_space(3)))

__device__ __forceinline__ unsigned int cvtpk(float lo, float hi) {
  unsigned int r;
  asm("v_cvt_pk_bf16_f32 %0, %1, %2" : "=v"(r) : "v"(lo), "v"(hi));
  return r;
}
__device__ __forceinline__ unsigned short f2bf(float f) { return (unsigned short)cvtpk(f, f); }
__device__ __forceinline__ f32x4 mfma16(bf16x8 a, bf16x8 b, f32x4 c) {
  return __builtin_amdgcn_mfma_f32_16x16x32_bf16(a, b, c, 0, 0, 0);
}
__device__ __forceinline__ void gl_lds16(const unsigned short* g, unsigned short* l) {
  __builtin_amdgcn_global_load_lds((const GAS unsigned short*)g, (LAS unsigned short*)l, 16, 0, 0);
}
__device__ __forceinline__ void memfence_sched() { asm volatile("" ::: "memory"); }

__global__ __launch_bounds__(256)
void cvt_f32_bf16(const float* __restrict__ in, unsigned short* __restrict__ out, int n8) {
  for (int i = blockIdx.x * blockDim.x + threadIdx.x; i < n8; i += gridDim.x * blockDim.x) {
    const float4 a = *reinterpret_cast<const float4*>(in + (size_t)i * 8);
    const float4 b = *reinterpret_cast<const float4*>(in + (size_t)i * 8 + 4);
    uint4 o;
    o.x = cvtpk(a.x, a.y); o.y = cvtpk(a.z, a.w);
    o.z = cvtpk(b.x, b.y); o.w = cvtpk(b.z, b.w);
    *reinterpret_cast<uint4*>(out + (size_t)i * 8) = o;
  }
}

// C[M,N] = A[M,512] @ B[N,512]^T.  128x128 tile, BK=32, 16 K-steps,
// 256 thr (4 waves 2x2), per-wave 64x64 (acc[4][4] -> 3 blocks/CU; m97/m114).
// PURE (!AF32): BOTH operands bf16 via global_load_lds, depth-2 counted:
//   top of iter kt issues G(kt+2) (4 loads); end s_waitcnt vmcnt(4) forces
//   G(kt+1), leaves G(kt+2) in flight (never drains until tail). 3 LDS
//   slots/operand = 48 KB. This is the m97 structure (874-912 TF measured).
// MIXED (AF32): round-13 path verbatim (A fp32 reg-staged depth-2 + cvt_pk,
//   B gl_lds depth-1, 2 slots each). Used only for the small q-GEMM.
// Swizzle (both): LDS chunk = global chunk ^ ((row>>1)&3), pre-swizzled src,
//   same key on ds_read (round-6/13 scheme, SQ_LDS_BANK_CONFLICT = 0).
// MODE 0: bf16 out *0.125 ; MODE 2: f32 out + bias ;
// MODE 3: fused kv epilogue — col0<512 -> k rows ; col0>=512 -> vT transpose.
template<int MODE, bool AF32>
__global__ __launch_bounds__(256, 3)
void gemmM(const void* __restrict__ Agv, const unsigned short* __restrict__ Bg,
           void* __restrict__ Cg, void* __restrict__ Cg2,
           const float* __restrict__ bias, int ntn, size_t ldc)
{
  constexpr int NS = AF32 ? 2 : 3;               // LDS slots per operand
  __shared__ unsigned short sm[NS * 2 * 4096];   // A: slot*4096 ; B: +NS*4096
  unsigned short* const smB = sm + NS * 4096;

  const int t = threadIdx.x, lane = t & 63, w = t >> 6;
  const int lo = lane & 15, hi = lane >> 4;
  const int wm = w >> 1, wn = w & 1;
  const int nwg = gridDim.x, bid = blockIdx.x;
  const int id = (bid & 7) * (nwg >> 3) + (bid >> 3);   // XCD swizzle (nwg%8==0)
  const int row0 = (id / ntn) * 128, col0 = (id % ntn) * 128;

  const float* Af = (const float*)Agv;
  const unsigned short* Ab = (const unsigned short*)Agv;

  // gl_lds addressing (pre-swizzled source)
  const int swcol = ((lane & 3) ^ ((lane >> 3) & 3)) * 8;
  const unsigned short* bS = Bg + (size_t)(col0 + w * 32 + (lane >> 2)) * 512 + swcol;
  const unsigned short* aSg = Ab + (size_t)(row0 + w * 32 + (lane >> 2)) * 512 + swcol;

  // fp32 reg-staged addressing (MIXED only)
  const int rs_r = t >> 2;
  const int rs_c = (t & 3) * 8;
  const int wch = ((t & 3) ^ ((t >> 3) & 3)) * 8;

  float4 stF[2][4];

  auto F_ISSUE = [&](int kt) {
    if constexpr (AF32) {
      const int bk = kt & 1;
      const float* s0 = Af + (size_t)(row0 + rs_r) * 512 + kt * 32 + rs_c;
      const float* s1 = Af + (size_t)(row0 + 64 + rs_r) * 512 + kt * 32 + rs_c;
      stF[bk][0] = *(const float4*)s0; stF[bk][1] = *(const float4*)(s0 + 4);
      stF[bk][2] = *(const float4*)s1; stF[bk][3] = *(const float4*)(s1 + 4);
    }
  };
  auto F_WRITE = [&](int kt) {
    if constexpr (AF32) {
      const int bk = kt & 1;
      unsigned short* fb = &sm[(kt % NS) * 4096];
      uint4 o;
      o.x = cvtpk(stF[bk][0].x, stF[bk][0].y); o.y = cvtpk(stF[bk][0].z, stF[bk][0].w);
      o.z = cvtpk(stF[bk][1].x, stF[bk][1].y); o.w = cvtpk(stF[bk][1].z, stF[bk][1].w);
      *reinterpret_cast<uint4*>(&fb[rs_r * 32 + wch]) = o;
      o.x = cvtpk(stF[bk][2].x, stF[bk][2].y); o.y = cvtpk(stF[bk][2].z, stF[bk][2].w);
      o.z = cvtpk(stF[bk][3].x, stF[bk][3].y); o.w = cvtpk(stF[bk][3].z, stF[bk][3].w);
      *reinterpret_cast<uint4*>(&fb[(64 + rs_r) * 32 + wch]) = o;
    }
  };
  auto G_ISSUE = [&](int kt) {
    unsigned short* bb = &smB[(kt % NS) * 4096];
    gl_lds16(bS + kt * 32,                    bb + (w * 2 + 0) * 512);
    gl_lds16(bS + (size_t)16 * 512 + kt * 32, bb + (w * 2 + 1) * 512);
    if constexpr (!AF32) {
      unsigned short* ab = &sm[(kt % NS) * 4096];
      gl_lds16(aSg + kt * 32,                    ab + (w * 2 + 0) * 512);
      gl_lds16(aSg + (size_t)16 * 512 + kt * 32, ab + (w * 2 + 1) * 512);
    }
  };

  f32x4 acc[4][4] = {};
  const int fxor = (hi ^ ((lo >> 1) & 3)) * 8;

  // ---- prologue ----
  if constexpr (AF32) {
    F_ISSUE(0);
    G_ISSUE(0);
    F_ISSUE(1);
    memfence_sched();
    asm volatile("s_waitcnt vmcnt(6)" ::: "memory");   // F(0) done
    F_WRITE(0);
    asm volatile("s_waitcnt vmcnt(4)" ::: "memory");   // G(0) done
  } else {
    G_ISSUE(0); G_ISSUE(1);                            // 8 loads
    memfence_sched();
    asm volatile("s_waitcnt vmcnt(4)" ::: "memory");   // tile0 done, tile1 in flight
  }
  asm volatile("s_waitcnt lgkmcnt(0)" ::: "memory");
  __builtin_amdgcn_s_barrier();
  memfence_sched();

  // ---- main loop ----
  #pragma unroll
  for (int kt = 0; kt < 16; ++kt) {
    const unsigned short* ab = &sm[(kt % NS) * 4096];
    const unsigned short* bb = &smB[(kt % NS) * 4096];
    bf16x8 bfr[4], af[4];
    #pragma unroll
    for (int nj = 0; nj < 4; ++nj)
      bfr[nj] = *reinterpret_cast<const bf16x8*>(&bb[(wn * 64 + nj * 16 + lo) * 32 + fxor]);
    #pragma unroll
    for (int mi = 0; mi < 4; ++mi)
      af[mi] = *reinterpret_cast<const bf16x8*>(&ab[(wm * 64 + mi * 16 + lo) * 32 + fxor]);

    if constexpr (AF32) {
      if (kt <= 14) G_ISSUE(kt + 1);
      if (kt <= 13) F_ISSUE(kt + 2);
    } else {
      if (kt <= 13) G_ISSUE(kt + 2);
    }
    memfence_sched();

    __builtin_amdgcn_s_setprio(1);
    #pragma unroll
    for (int mi = 0; mi < 2; ++mi)
      #pragma unroll
      for (int nj = 0; nj < 4; ++nj)
        acc[mi][nj] = mfma16(af[mi], bfr[nj], acc[mi][nj]);
    __builtin_amdgcn_s_setprio(0);

    if constexpr (AF32) {
      if (kt <= 13)      { asm volatile("s_waitcnt vmcnt(6)" ::: "memory"); }
      else if (kt == 14) { asm volatile("s_waitcnt vmcnt(2)" ::: "memory"); }
      if (kt <= 14) F_WRITE(kt + 1);
    }

    __builtin_amdgcn_s_setprio(1);
    #pragma unroll
    for (int mi = 2; mi < 4; ++mi)
      #pragma unroll
      for (int nj = 0; nj < 4; ++nj)
        acc[mi][nj] = mfma16(af[mi], bfr[nj], acc[mi][nj]);
    __builtin_amdgcn_s_setprio(0);

    if (kt < 15) {
      if constexpr (AF32) {
        if (kt <= 13) { asm volatile("s_waitcnt vmcnt(4)" ::: "memory"); }
        else          { asm volatile("s_waitcnt vmcnt(0)" ::: "memory"); }
      } else {
        if (kt <= 13) { asm volatile("s_waitcnt vmcnt(4)" ::: "memory"); }  // kt+1 ready
        else          { asm volatile("s_waitcnt vmcnt(0)" ::: "memory"); }  // tail drain
      }
      asm volatile("s_waitcnt lgkmcnt(0)" ::: "memory");
      __builtin_amdgcn_s_barrier();
      memfence_sched();
    }
  }

  if constexpr (MODE == 3) {
    // fused kv epilogue; per-wave private 4096-ush bounce region
    __syncthreads();
    unsigned short* Tb = &sm[w * 4096];
    if (col0 < 512) {
      // k-part: straight bounce [64 gm][64 gn]; b128 row stores
      #pragma unroll
      for (int q = 0; q < 4; ++q)
        #pragma unroll
        for (int nj = 0; nj < 4; ++nj)
          #pragma unroll
          for (int r = 0; r < 4; ++r)
            Tb[(q * 16 + hi * 4 + r) * 64 + nj * 16 + lo] = f2bf(acc[q][nj][r]);
      asm volatile("s_waitcnt lgkmcnt(0)" ::: "memory");
      #pragma unroll
      for (int it = 0; it < 8; ++it) {
        const int rr = it * 8 + (lane >> 3);
        const bf16x8 v = *reinterpret_cast<const bf16x8*>(&Tb[rr * 64 + (lane & 7) * 8]);
        const size_t gm = (size_t)row0 + wm * 64 + rr;
        *reinterpret_cast<bf16x8*>((unsigned short*)Cg + gm * 512 + col0 + wn * 64 +
                                   (lane & 7) * 8) = v;
      }
    } else {
      // v-part: transpose bounce [64 gn][64 gm], row-keyed xor gm^=(gn&15)*4
      #pragma unroll
      for (int q = 0; q < 4; ++q)
        #pragma unroll
        for (int nj = 0; nj < 4; ++nj)
          #pragma unroll
          for (int r = 0; r < 4; ++r) {
            const int gn_l = nj * 16 + lo;
            const int gm_l = (q * 16 + hi * 4 + r) ^ ((gn_l & 15) * 4);
            Tb[gn_l * 64 + gm_l] = f2bf(acc[q][nj][r]);
          }
      asm volatile("s_waitcnt lgkmcnt(0)" ::: "memory");
      #pragma unroll
      for (int it = 0; it < 16; ++it) {
        const int gn_l = it * 4 + (lane >> 4);
        const int g4 = ((lane & 15) * 4) ^ ((gn_l & 15) * 4);
        const ush4 v = *reinterpret_cast<const ush4*>(&Tb[gn_l * 64 + g4]);
        const size_t vrow = (size_t)(col0 - 512) + wn * 64 + gn_l;
        const size_t vcol = (size_t)row0 + wm * 64 + (lane & 15) * 4;
        *reinterpret_cast<ush4*>((unsigned short*)Cg2 + vrow * 131072 + vcol) = v;
      }
    }
  } else {
    #pragma unroll
    for (int mi = 0; mi < 4; ++mi) {
      #pragma unroll
      for (int r = 0; r < 4; ++r) {
        const size_t gm = (size_t)row0 + wm * 64 + mi * 16 + hi * 4 + r;
        #pragma unroll
        for (int nj = 0; nj < 4; ++nj) {
          const int gn = col0 + wn * 64 + nj * 16 + lo;
          const float v = acc[mi][nj][r];
          if constexpr (MODE == 0)
            ((unsigned short*)Cg)[gm * ldc + gn] = f2bf(v * 0.125f);
          else
            ((float*)Cg)[gm * ldc + gn] = v + bias[gn];
        }
      }
    }
  }
}

// Flash attention, KV split 4-way: grid = 2048 (b,h,qhalf,chunk), 256 thr
// (4 waves x 16 q-rows). Writes partials (o fp32, m, l) for combine pass.
// k [131072, 512] bf16 (col h*64+d); vT [512, 131072] bf16.
__global__ __launch_bounds__(256)
void attn_fwd(const unsigned short* __restrict__ qh,
              const unsigned short* __restrict__ kbuf,
              const unsigned short* __restrict__ vT,
              const float* __restrict__ mask,
              float* __restrict__ opart, float* __restrict__ ml)
{
  __shared__ unsigned short Ks[64 * 64];
  __shared__ unsigned short Vs[64 * 64];
  __shared__ unsigned short Ps[4][16 * 64];
  const int bid = blockIdx.x;
  const int xcd = bid & 7, g = bid >> 3;
  const int b = (g >> 6) * 8 + xcd;
  const int sub = g & 63;
  const int h = sub >> 3, qhalf = (sub >> 2) & 1, c = sub & 3;
  const int n0 = c * 1024;
  const int bh2 = (b * 8 + h) * 2 + qhalf;
  const int t = threadIdx.x, lane = t & 63, w = t >> 6;
  const int hi = lane >> 4, lo = lane & 15;
  const int q0 = qhalf * 64 + w * 16;

  bf16x8 aq[2];
  #pragma unroll
  for (int kk = 0; kk < 2; ++kk)
    aq[kk] = *reinterpret_cast<const bf16x8*>(
        qh + (size_t)(b * 128 + q0 + lo) * 512 + h * 64 + kk * 32 + hi * 8);

  float mrow[4], lrow[4];
  #pragma unroll
  for (int i = 0; i < 4; ++i) { mrow[i] = -1e30f; lrow[i] = 0.f; }
  f32x4 o[4] = {};

  const unsigned short* kp = kbuf + ((size_t)b * 4096 + n0) * 512 + h * 64;
  const unsigned short* vp = vT + (size_t)(h * 64) * 131072 + (size_t)b * 4096 + n0;
  const float* mp = mask + ((size_t)(b * 128 + q0)) * 4096 + n0;

  for (int nt = 0; nt < 16; ++nt) {
    {
      const int r = t >> 3, cc = t & 7;
      *reinterpret_cast<uint4*>(&Ks[r * 64 + ((cc ^ (r & 7)) << 3)]) =
          *reinterpret_cast<const uint4*>(kp + (size_t)(nt * 64 + r) * 512 + (cc << 3));
      *reinterpret_cast<uint4*>(&Ks[(r + 32) * 64 + ((cc ^ (r & 7)) << 3)]) =
          *reinterpret_cast<const uint4*>(kp + (size_t)(nt * 64 + r + 32) * 512 + (cc << 3));
      *reinterpret_cast<uint4*>(&Vs[r * 64 + ((cc ^ (r & 7)) << 3)]) =
          *reinterpret_cast<const uint4*>(vp + (size_t)r * 131072 + nt * 64 + (cc << 3));
      *reinterpret_cast<uint4*>(&Vs[(r + 32) * 64 + ((cc ^ (r & 7)) << 3)]) =
          *reinterpret_cast<const uint4*>(vp + (size_t)(r + 32) * 131072 + nt * 64 + (cc << 3));
    }
    __syncthreads();

    f32x4 s[4] = {};
    __builtin_amdgcn_s_setprio(1);
    #pragma unroll
    for (int ni = 0; ni < 4; ++ni) {
      #pragma unroll
      for (int kk = 0; kk < 2; ++kk) {
        const bf16x8 kf = *reinterpret_cast<const bf16x8*>(
            &Ks[(ni * 16 + lo) * 64 + ((kk * 32 + hi * 8) ^ ((lo & 7) << 3))]);
        s[ni] = mfma16(aq[kk], kf, s[ni]);
      }
    }
    __builtin_amdgcn_s_setprio(0);
    #pragma unroll
    for (int ni = 0; ni < 4; ++ni)
      #pragma unroll
      for (int r = 0; r < 4; ++r)
        s[ni][r] += mp[(size_t)(hi * 4 + r) * 4096 + nt * 64 + ni * 16 + lo];

    #pragma unroll
    for (int r = 0; r < 4; ++r) {
      float mx = fmaxf(fmaxf(s[0][r], s[1][r]), fmaxf(s[2][r], s[3][r]));
      #pragma unroll
      for (int off = 1; off < 16; off <<= 1)
        mx = fmaxf(mx, __shfl_xor(mx, off, 64));
      const float mnew = fmaxf(mrow[r], mx);
      const float corr = __expf(mrow[r] - mnew);
      mrow[r] = mnew;
      float ls = 0.f;
      #pragma unroll
      for (int ni = 0; ni < 4; ++ni) {
        const float p = __expf(s[ni][r] - mnew);
        s[ni][r] = p; ls += p;
      }
      #pragma unroll
      for (int off = 1; off < 16; off <<= 1)
        ls += __shfl_xor(ls, off, 64);
      lrow[r] = lrow[r] * corr + ls;
      #pragma unroll
      for (int di = 0; di < 4; ++di)
        o[di][r] *= corr;
    }

    #pragma unroll
    for (int ni = 0; ni < 4; ++ni)
      #pragma unroll
      for (int r = 0; r < 4; ++r) {
        const int rp = hi * 4 + r;
        Ps[w][rp * 64 + ((ni * 16 + lo) ^ ((rp & 7) << 3))] = f2bf(s[ni][r]);
      }

    __builtin_amdgcn_s_setprio(1);
    #pragma unroll
    for (int kk = 0; kk < 2; ++kk) {
      const bf16x8 pa = *reinterpret_cast<const bf16x8*>(
          &Ps[w][lo * 64 + ((kk * 32 + hi * 8) ^ ((lo & 7) << 3))]);
      #pragma unroll
      for (int di = 0; di < 4; ++di) {
        const bf16x8 vf = *reinterpret_cast<const bf16x8*>(
            &Vs[(di * 16 + lo) * 64 + ((kk * 32 + hi * 8) ^ ((lo & 7) << 3))]);
        o[di] = mfma16(pa, vf, o[di]);
      }
    }
    __builtin_amdgcn_s_setprio(0);
    __syncthreads();
  }

  const size_t pbase = ((size_t)bh2 * 4 + c) * 64;
  #pragma unroll
  for (int di = 0; di < 4; ++di)
    #pragma unroll
    for (int r = 0; r < 4; ++r)
      opart[(pbase + (w * 16 + hi * 4 + r)) * 64 + di * 16 + lo] = o[di][r];
  if (lo == 0) {
    #pragma unroll
    for (int r = 0; r < 4; ++r) {
      const int qq = w * 16 + hi * 4 + r;
      ml[(((size_t)bh2 * 4 + c) * 2 + 0) * 64 + qq] = mrow[r];
      ml[(((size_t)bh2 * 4 + c) * 2 + 1) * 64 + qq] = lrow[r];
    }
  }
}

// Combine 4 chunk-partials -> xb bf16. grid = 512 (bh2), 256 thr.
__global__ __launch_bounds__(256)
void attn_combine(const float* __restrict__ opart, const float* __restrict__ ml,
                  unsigned short* __restrict__ xb)
{
  const int bh2 = blockIdx.x;
  const int b = bh2 >> 4, h = (bh2 >> 1) & 7, qhalf = bh2 & 1;
  const int t = threadIdx.x;
  const int q = t >> 2, dg = t & 3;

  float m[4], l[4];
  #pragma unroll
  for (int c = 0; c < 4; ++c) {
    m[c] = ml[(((size_t)bh2 * 4 + c) * 2 + 0) * 64 + q];
    l[c] = ml[(((size_t)bh2 * 4 + c) * 2 + 1) * 64 + q];
  }
  const float M = fmaxf(fmaxf(m[0], m[1]), fmaxf(m[2], m[3]));
  float sc[4], L = 0.f;
  #pragma unroll
  for (int c = 0; c < 4; ++c) { sc[c] = __expf(m[c] - M); L += sc[c] * l[c]; }
  const float inv = 1.f / L;

  float4 acc[4] = {};
  #pragma unroll
  for (int c = 0; c < 4; ++c) {
    const float* base = opart + (((size_t)bh2 * 4 + c) * 64 + q) * 64 + dg * 16;
    #pragma unroll
    for (int j = 0; j < 4; ++j) {
      const float4 v = *reinterpret_cast<const float4*>(base + j * 4);
      acc[j].x = fmaf(sc[c], v.x, acc[j].x);
      acc[j].y = fmaf(sc[c], v.y, acc[j].y);
      acc[j].z = fmaf(sc[c], v.z, acc[j].z);
      acc[j].w = fmaf(sc[c], v.w, acc[j].w);
    }
  }
  unsigned short* dst = xb + ((size_t)b * 128 + qhalf * 64 + q) * 512 + h * 64 + dg * 16;
  uint4 o1, o2;
  o1.x = cvtpk(acc[0].x * inv, acc[0].y * inv); o1.y = cvtpk(acc[0].z * inv, acc[0].w * inv);
  o1.z = cvtpk(acc[1].x * inv, acc[1].y * inv); o1.w = cvtpk(acc[1].z * inv, acc[1].w * inv);
  o2.x = cvtpk(acc[2].x * inv, acc[2].y * inv); o2.y = cvtpk(acc[2].z * inv, acc[2].w * inv);
  o2.z = cvtpk(acc[3].x * inv, acc[3].y * inv); o2.w = cvtpk(acc[3].z * inv, acc[3].w * inv);
  *reinterpret_cast<uint4*>(dst) = o1;
  *reinterpret_cast<uint4*>(dst + 8) = o2;
}

extern "C" void kernel_launch(void* const* d_in, const int* in_sizes, int n_in,
                              void* d_out, int out_size, void* d_ws, size_t ws_size,
                              hipStream_t stream) {
  const float* q     = (const float*)d_in[0];
  const float* kv    = (const float*)d_in[1];
  const float* mask  = (const float*)d_in[2];
  const float* Wq    = (const float*)d_in[3];
  const float* Wkv   = (const float*)d_in[4];
  const float* Wproj = (const float*)d_in[5];
  const float* bproj = (const float*)d_in[6];
  float* out = (float*)d_out;

  char* ws = (char*)d_ws;
  unsigned short* kbuf   = (unsigned short*)ws;                      // 134.2 MB [131072,512]
  unsigned short* vTb    = (unsigned short*)(ws + 134217728ULL);     // 134.2 MB [512,131072]
  unsigned short* kvbfc  = (unsigned short*)(ws + 268435456ULL);     // 67.1 MB rotating bf16 chunk
  float*          opart  = (float*)(ws + 268435456ULL);              // 33.6 MB (alias, post-chunk)
  float*          mlb    = (float*)(ws + 301989888ULL);              // 1.0 MB  (alias, post-chunk)
  unsigned short* xb     = (unsigned short*)(ws + 303038464ULL);     // 4.2 MB  (alias, post-chunk)
  unsigned short* qhb    = (unsigned short*)(ws + 335544320ULL);     // 4.2 MB
  unsigned short* Wqb    = (unsigned short*)(ws + 339738624ULL);     // 0.5 MB
  unsigned short* Wkvb   = (unsigned short*)(ws + 340262912ULL);     // 1.0 MB
  unsigned short* Wprojb = (unsigned short*)(ws + 341311488ULL);     // 0.5 MB

  cvt_f32_bf16<<<128, 256, 0, stream>>>(Wq, Wqb, 512 * 512 / 8);
  cvt_f32_bf16<<<256, 256, 0, stream>>>(Wkv, Wkvb, 1024 * 512 / 8);
  cvt_f32_bf16<<<128, 256, 0, stream>>>(Wproj, Wprojb, 512 * 512 / 8);

  // qh = (q @ Wq^T) * scale        M=4096, N=512  (A fp32, MIXED — tiny)
  gemmM<0, true><<<128, 256, 0, stream>>>(q, Wqb, qhb, nullptr, nullptr, 4, 512);

  // fused kv projection, 2 chunks: cvt fp32->bf16, then pure-bf16 GEMM
  for (int c = 0; c < 2; ++c) {
    cvt_f32_bf16<<<2048, 256, 0, stream>>>(kv + (size_t)c * 65536 * 512, kvbfc,
                                           65536 * 512 / 8);
    gemmM<3, false><<<4096, 256, 0, stream>>>(kvbfc, Wkvb,
                                              kbuf + (size_t)c * 65536 * 512,
                                              vTb + (size_t)c * 65536, nullptr, 8, 512);
  }

  // flash attention partials
  attn_fwd<<<2048, 256, 0, stream>>>(qhb, kbuf, vTb, mask, opart, mlb);
  // combine -> xb bf16
  attn_combine<<<512, 256, 0, stream>>>(opart, mlb, xb);
  // out = x @ Wproj^T + bproj     (pure bf16)
  gemmM<2, false><<<128, 256, 0, stream>>>(xb, Wprojb, out, nullptr, bproj, 4, 512);
}